// Round 1
// baseline (576.945 us; speedup 1.0000x reference)
//
#include <hip/hip_runtime.h>

// O(2) full tensor product:
//   input1: (2048, 448)  irreps [(64,m=0),(64,m=1),(64,m=2),(64,m=3)]
//   input2: (2048, 160)  irreps [(32,m=0),(32,m=1),(32,m=2)]
//   output: (2048, 71680) — 20 CG-path chunks, sorted by (m_out, -parity)
//
// All CG normalization factors reduce to: 1.0 (scalar*scalar),
// sqrt(2) (scalar*vector paths), 1.0 (vec*vec -> vec, since sqrt(2)*R2=1),
// 1/sqrt(2) (vec*vec -> scalar/pseudoscalar).
//
// Write-BW-bound kernel: 587 MB out vs 5 MB in. One block per batch row,
// inputs staged in LDS, all stores are coalesced float4.

#define R2F  0.70710678118654752440f
#define SQ2F 1.41421356237309504880f

constexpr int BATCH = 2048;
constexpr int DIM1  = 448;
constexpr int DIM2  = 160;
constexpr int ODIM  = 71680;   // per-batch output floats (17920 float4)

__global__ __launch_bounds__(256)
void tp_kernel(const float* __restrict__ g1, const float* __restrict__ g2,
               float* __restrict__ gout) {
    const int b  = blockIdx.x;
    const int t0 = threadIdx.x;

    __shared__ float s1[DIM1];
    __shared__ float s2[DIM2];
    {
        const float* x1 = g1 + (size_t)b * DIM1;
        const float* x2 = g2 + (size_t)b * DIM2;
        for (int i = t0; i < DIM1; i += 256) s1[i] = x1[i];
        for (int i = t0; i < DIM2; i += 256) s2[i] = x2[i];
    }
    __syncthreads();

    float4* out = (float4*)(gout + (size_t)b * ODIM);

    // ---- scalar-output chunks: 2048 floats = 512 float4; pos=4t, u=t>>3, v=4t&31
    // ss: out[u*32+v] = a[u]*b[v]
    auto chunk_ss = [&](int dst4, const float* a, const float* b) {
#pragma unroll
        for (int r = 0; r < 2; ++r) {
            int t = t0 + r * 256;
            int u = t >> 3;
            int v = (4 * t) & 31;
            float au = a[u];
            out[dst4 + t] = make_float4(au * b[v], au * b[v + 1],
                                        au * b[v + 2], au * b[v + 3]);
        }
    };
    // cos(a-b) scalar: R2*(ac*bc + as*bs)
    auto chunk_cos = [&](int dst4, const float* a, const float* b) {
#pragma unroll
        for (int r = 0; r < 2; ++r) {
            int t = t0 + r * 256;
            int u = t >> 3;
            int v = (4 * t) & 31;
            float ac = R2F * a[2 * u], as = R2F * a[2 * u + 1];
            float4 res;
            res.x = ac * b[2 * v + 0] + as * b[2 * v + 1];
            res.y = ac * b[2 * v + 2] + as * b[2 * v + 3];
            res.z = ac * b[2 * v + 4] + as * b[2 * v + 5];
            res.w = ac * b[2 * v + 6] + as * b[2 * v + 7];
            out[dst4 + t] = res;
        }
    };
    // sin(a-b) pseudoscalar: R2*(as*bc - ac*bs)
    auto chunk_sin = [&](int dst4, const float* a, const float* b) {
#pragma unroll
        for (int r = 0; r < 2; ++r) {
            int t = t0 + r * 256;
            int u = t >> 3;
            int v = (4 * t) & 31;
            float ac = R2F * a[2 * u], as = R2F * a[2 * u + 1];
            float4 res;
            res.x = as * b[2 * v + 0] - ac * b[2 * v + 1];
            res.y = as * b[2 * v + 2] - ac * b[2 * v + 3];
            res.z = as * b[2 * v + 4] - ac * b[2 * v + 5];
            res.w = as * b[2 * v + 6] - ac * b[2 * v + 7];
            out[dst4 + t] = res;
        }
    };

    // ---- vector-output chunks: 4096 floats = 1024 float4
    // float4 t covers (u,v,k=0..1),(u,v+1,k=0..1): u=t>>4, v=(2t)&31
    // scalar x vector: out[(u*32+v)*2+k] = sqrt2 * a[u] * b[2v+k]
    auto chunk_sv = [&](int dst4, const float* a, const float* b) {
#pragma unroll
        for (int r = 0; r < 4; ++r) {
            int t = t0 + r * 256;
            int u = t >> 4;
            int v = (2 * t) & 31;
            float au = SQ2F * a[u];
            out[dst4 + t] = make_float4(au * b[2 * v + 0], au * b[2 * v + 1],
                                        au * b[2 * v + 2], au * b[2 * v + 3]);
        }
    };
    // vector x scalar: out[(u*32+v)*2+k] = sqrt2 * a[2u+k] * b[v]
    auto chunk_vs = [&](int dst4, const float* a, const float* b) {
#pragma unroll
        for (int r = 0; r < 4; ++r) {
            int t = t0 + r * 256;
            int u = t >> 4;
            int v = (2 * t) & 31;
            float ac = SQ2F * a[2 * u], as = SQ2F * a[2 * u + 1];
            out[dst4 + t] = make_float4(ac * b[v], as * b[v],
                                        ac * b[v + 1], as * b[v + 1]);
        }
    };
    // m1+m2 path: k0 = ac*bc - as*bs ; k1 = as*bc + ac*bs   (coef 1)
    auto chunk_sum = [&](int dst4, const float* a, const float* b) {
#pragma unroll
        for (int r = 0; r < 4; ++r) {
            int t = t0 + r * 256;
            int u = t >> 4;
            int v = (2 * t) & 31;
            float ac = a[2 * u], as = a[2 * u + 1];
            float bc0 = b[2 * v + 0], bs0 = b[2 * v + 1];
            float bc1 = b[2 * v + 2], bs1 = b[2 * v + 3];
            out[dst4 + t] = make_float4(ac * bc0 - as * bs0, as * bc0 + ac * bs0,
                                        ac * bc1 - as * bs1, as * bc1 + ac * bs1);
        }
    };
    // |m1-m2| path: k0 = ac*bc + as*bs ; k1 = sgn*(as*bc - ac*bs)  (coef 1)
    auto chunk_diff = [&](int dst4, const float* a, const float* b, float sgn) {
#pragma unroll
        for (int r = 0; r < 4; ++r) {
            int t = t0 + r * 256;
            int u = t >> 4;
            int v = (2 * t) & 31;
            float ac = a[2 * u], as = a[2 * u + 1];
            float bc0 = b[2 * v + 0], bs0 = b[2 * v + 1];
            float bc1 = b[2 * v + 2], bs1 = b[2 * v + 3];
            out[dst4 + t] = make_float4(ac * bc0 + as * bs0, sgn * (as * bc0 - ac * bs0),
                                        ac * bc1 + as * bs1, sgn * (as * bc1 - ac * bs1));
        }
    };

    // s1 blocks: m=0 @0, m=1 @64, m=2 @192, m=3 @320
    // s2 blocks: m=0 @0, m=1 @32, m=2 @96
    // Output chunk order (stable sort by (m_out, -parity)); dst in float4 units.
    chunk_ss  (    0, s1 +   0, s2 +  0);        // (0x0 ->0+)   off 0
    chunk_cos (  512, s1 +  64, s2 + 32);        // (1x1 ->0+)   off 2048
    chunk_cos ( 1024, s1 + 192, s2 + 96);        // (2x2 ->0+)   off 4096
    chunk_sin ( 1536, s1 +  64, s2 + 32);        // (1x1 ->0-)   off 6144
    chunk_sin ( 2048, s1 + 192, s2 + 96);        // (2x2 ->0-)   off 8192
    chunk_sv  ( 2560, s1 +   0, s2 + 32);        // (0x1 ->1)    off 10240
    chunk_vs  ( 3584, s1 +  64, s2 +  0);        // (1x0 ->1)    off 14336
    chunk_diff( 4608, s1 +  64, s2 + 96, -1.f);  // (1x2 ->1)    off 18432
    chunk_diff( 5632, s1 + 192, s2 + 32, +1.f);  // (2x1 ->1)    off 22528
    chunk_diff( 6656, s1 + 320, s2 + 96, +1.f);  // (3x2 ->1)    off 26624
    chunk_sv  ( 7680, s1 +   0, s2 + 96);        // (0x2 ->2)    off 30720
    chunk_sum ( 8704, s1 +  64, s2 + 32);        // (1x1 ->2)    off 34816
    chunk_vs  ( 9728, s1 + 192, s2 +  0);        // (2x0 ->2)    off 38912
    chunk_diff(10752, s1 + 320, s2 + 32, +1.f);  // (3x1 ->2)    off 43008
    chunk_sum (11776, s1 +  64, s2 + 96);        // (1x2 ->3)    off 47104
    chunk_sum (12800, s1 + 192, s2 + 32);        // (2x1 ->3)    off 51200
    chunk_vs  (13824, s1 + 320, s2 +  0);        // (3x0 ->3)    off 55296
    chunk_sum (14848, s1 + 192, s2 + 96);        // (2x2 ->4)    off 59392
    chunk_sum (15872, s1 + 320, s2 + 32);        // (3x1 ->4)    off 63488
    chunk_sum (16896, s1 + 320, s2 + 96);        // (3x2 ->5)    off 67584
}

extern "C" void kernel_launch(void* const* d_in, const int* in_sizes, int n_in,
                              void* d_out, int out_size, void* d_ws, size_t ws_size,
                              hipStream_t stream) {
    const float* x1 = (const float*)d_in[0];
    const float* x2 = (const float*)d_in[1];
    float* out = (float*)d_out;
    tp_kernel<<<BATCH, 256, 0, stream>>>(x1, x2, out);
}